// Round 5
// baseline (123.416 us; speedup 1.0000x reference)
//
#include <hip/hip_runtime.h>

// VectorQuantizer: x (64,32,32,128) f32, embeddings (128,1024) f32.
// out = x + (q - x), q = e.T[argmin_k ||x_row - e_k||^2]   (same f32 ops as ref)
//
// Cascade:
//   phase 1: split-bf16 MFMA (32x32x16): dot = xh.eh + xh.el + xl.eh (3 MFMAs,
//            f32 acc). score = nrm32[k] - 2*dot. sigma ~ 1e-4.
//            Grid = 512 rowgroups x 2 code-halves (occupancy 2x).
//   merge  : combine the 2 halves per row; gap < MARGIN1 -> worklist (~40 rows).
//   phase 2: f64 exact re-argmin of worklist rows (one row per block).
// A/B packed with the SAME k-bijection (dot invariant to consistent k-perm).
// C/D layout: col=lane&31, row=(reg&3)+8*(reg>>2)+4*(lane>>5)  [HW-verified].

#define NROWS 65536
#define DDIM 128
#define KCODES 1024
#define MARGIN1 0.004f

typedef __attribute__((ext_vector_type(8))) short short8;
typedef __attribute__((ext_vector_type(16))) float f32x16;

__device__ inline ushort f2bf(float f) {            // RNE f32 -> bf16 bits
    union { float f; unsigned u; } v; v.f = f;
    unsigned r = v.u + 0x7fffu + ((v.u >> 16) & 1u);
    return (ushort)(r >> 16);
}
__device__ inline float bf2f(ushort b) {
    union { unsigned u; float f; } v; v.u = ((unsigned)b) << 16;
    return v.f;
}

__device__ inline void gload_lds16(const uint4* g, uint4* lds) {
    __builtin_amdgcn_global_load_lds((const __attribute__((address_space(1))) void*)g,
                                     (__attribute__((address_space(3))) void*)lds,
                                     16, 0, 0);
}

// ---------- fused prep: transpose + norms + bf16 hi/lo pack ----------
// grid 512 x 256 = 131072 threads.
__global__ void k_prep(const float* __restrict__ e, float* __restrict__ et,
                       float* __restrict__ nrm, double* __restrict__ nrm64,
                       uint4* __restrict__ epq) {
    const int gid = blockIdx.x * blockDim.x + threadIdx.x;

    // transpose (all threads): et[k][d] = e[d][k]
    {
        int d = gid >> 10, k = gid & 1023;
        et[k * DDIM + d] = e[gid];
    }

    // pack (first 32768 threads): epq slot = nt*1024 + h*512 + c*64 + lane
    if (gid < 32768) {
        int lane = gid & 63, c = (gid >> 6) & 7, h = (gid >> 9) & 1, nt = gid >> 10;
        int col = nt * 32 + (lane & 31);
        int kbase = c * 16 + ((lane >> 5) << 3);
        union { ushort u[8]; uint4 q; } pk;
        #pragma unroll
        for (int j = 0; j < 8; ++j) {
            float v = e[(kbase + j) * KCODES + col];
            ushort hb = f2bf(v);
            pk.u[j] = (h == 0) ? hb : f2bf(v - bf2f(hb));
        }
        epq[(size_t)nt * 1024 + h * 512 + c * 64 + lane] = pk.q;
    }

    // norms (threads 32768..40959): 8 lanes per code, 16 d each, shfl reduce
    if (gid >= 32768 && gid < 32768 + 8192) {
        int t2 = gid - 32768;
        int k = t2 >> 3, part = t2 & 7;
        double s = 0.0;
        #pragma unroll
        for (int j = 0; j < 16; ++j) {
            double v = (double)e[(part * 16 + j) * KCODES + k];
            s = fma(v, v, s);
        }
        #pragma unroll
        for (int m = 1; m < 8; m <<= 1) s += __shfl_xor(s, m);
        if (part == 0) { nrm64[k] = s; nrm[k] = (float)s; }
    }
}

// ---------- phase 1: split-bf16 MFMA argmin, code-split ----------
// grid 1024 = 512 rowgroups x 2 code-halves. Block = 4 waves = 4 rowtiles.
// Each block scans 16 e-tiles (512 codes), double-buffered via global_load_lds.
__global__ __launch_bounds__(256, 4) void k_argmin32(const float* __restrict__ x,
                                                     const uint4* __restrict__ epq,
                                                     const float* __restrict__ nrm,
                                                     float* __restrict__ pb1,
                                                     float* __restrict__ pb2,
                                                     int* __restrict__ pbi) {
    __shared__ uint4 sbuf[2][1024];                    // 32 KB

    const int tid = threadIdx.x;
    const int lane = tid & 63;
    const int w = tid >> 6;                            // rowtile in block
    const int kh = blockIdx.x & 1;                     // code half
    const int rg = blockIdx.x >> 1;
    const int rt = rg * 4 + w;
    const int lrow = lane & 31;
    const int lgrp = lane >> 5;
    const int tbase = kh * 16;

    // A fragments (hi/lo): row = rt*32+lrow, k(c,j) = c*16 + lgrp*8 + j
    const float* xr = x + (size_t)(rt * 32 + lrow) * DDIM + (lgrp << 3);
    short8 ah[8], al[8];
    #pragma unroll
    for (int c = 0; c < 8; ++c) {
        float4 u = *reinterpret_cast<const float4*>(xr + c * 16);
        float4 v = *reinterpret_cast<const float4*>(xr + c * 16 + 4);
        float fv[8] = {u.x, u.y, u.z, u.w, v.x, v.y, v.z, v.w};
        short8 hi, lo;
        #pragma unroll
        for (int j = 0; j < 8; ++j) {
            ushort hb = f2bf(fv[j]);
            hi[j] = (short)hb;
            lo[j] = (short)f2bf(fv[j] - bf2f(hb));
        }
        ah[c] = hi; al[c] = lo;
    }

    float b1[16], b2[16]; int bi[16];
    #pragma unroll
    for (int r = 0; r < 16; ++r) { b1[r] = 3.4e38f; b2[r] = 3.4e38f; bi[r] = 0; }

    // prologue: DMA tile tbase into sbuf[0]
    #pragma unroll
    for (int i = 0; i < 4; ++i)
        gload_lds16(epq + (size_t)tbase * 1024 + i * 256 + tid,
                    &sbuf[0][i * 256 + (w << 6)]);
    __syncthreads();

    int cur = 0;
    for (int t = 0; t < 16; ++t) {
        if (t + 1 < 16) {
            #pragma unroll
            for (int i = 0; i < 4; ++i)
                gload_lds16(epq + (size_t)(tbase + t + 1) * 1024 + i * 256 + tid,
                            &sbuf[cur ^ 1][i * 256 + (w << 6)]);
        }
        const int code = (tbase + t) * 32 + lrow;
        const float nv = nrm[code];

        f32x16 acc;
        #pragma unroll
        for (int r = 0; r < 16; ++r) acc[r] = 0.f;

        #pragma unroll
        for (int c = 0; c < 8; ++c) {
            union { uint4 q; short8 s; } bh, bl;
            bh.q = sbuf[cur][c * 64 + lane];
            bl.q = sbuf[cur][512 + c * 64 + lane];
            acc = __builtin_amdgcn_mfma_f32_32x32x16_bf16(ah[c], bh.s, acc, 0, 0, 0);
            acc = __builtin_amdgcn_mfma_f32_32x32x16_bf16(ah[c], bl.s, acc, 0, 0, 0);
            acc = __builtin_amdgcn_mfma_f32_32x32x16_bf16(al[c], bh.s, acc, 0, 0, 0);
        }

        #pragma unroll
        for (int r = 0; r < 16; ++r) {
            float s = fmaf(-2.f, acc[r], nv);
            bool lt = s < b1[r];
            b2[r] = lt ? b1[r] : fminf(b2[r], s);
            b1[r] = lt ? s : b1[r];
            bi[r] = lt ? code : bi[r];
        }
        __syncthreads();       // drains DMA (vmcnt) + guards buffer reuse
        cur ^= 1;
    }

    // butterfly over the 32 columns (each 32-lane half independently).
    // Tie-break across lanes unneeded: equal scores => gap 0 => flagged => k_fix.
    #pragma unroll
    for (int r = 0; r < 16; ++r) {
        #pragma unroll
        for (int m = 1; m < 32; m <<= 1) {
            float o1 = __shfl_xor(b1[r], m);
            float o2 = __shfl_xor(b2[r], m);
            int   oi = __shfl_xor(bi[r], m);
            bool take = (o1 < b1[r]) || (o1 == b1[r] && oi < bi[r]);
            float loser = take ? b1[r] : o1;
            b1[r] = take ? o1 : b1[r];
            bi[r] = take ? oi : bi[r];
            b2[r] = fminf(fminf(b2[r], o2), loser);
        }
    }

    if (lrow == 0) {
        #pragma unroll
        for (int r = 0; r < 16; ++r) {
            int rl = (r & 3) + 8 * (r >> 2) + 4 * lgrp;   // HW-verified C/D row map
            size_t o = (size_t)kh * NROWS + rt * 32 + rl;
            pb1[o] = b1[r]; pb2[o] = b2[r]; pbi[o] = bi[r];
        }
    }
}

// ---------- merge the 2 code-halves per row ----------
__global__ void k_merge(const float* __restrict__ pb1, const float* __restrict__ pb2,
                        const int* __restrict__ pbi, int* __restrict__ idx,
                        int* __restrict__ wlc, int* __restrict__ wl) {
    int r = blockIdx.x * blockDim.x + threadIdx.x;     // 0..NROWS-1
    float a1 = pb1[r], a2 = pb2[r];
    int   ai = pbi[r];
    float c1 = pb1[NROWS + r], c2 = pb2[NROWS + r];
    int   ci = pbi[NROWS + r];
    bool take = c1 < a1;                // tie -> half 0 (all its codes are lower)
    float f1 = take ? c1 : a1;
    int   fi = take ? ci : ai;
    float loser = take ? a1 : c1;
    float f2 = fminf(fminf(a2, c2), loser);
    idx[r] = fi;
    if (f2 - f1 < MARGIN1) {
        int slot = atomicAdd(wlc, 1);
        wl[slot] = r;
    }
}

// ---------- phase 2: exact f64 re-argmin, one row per block ----------
__global__ __launch_bounds__(256) void k_fix(const float* __restrict__ x,
                                             const float* __restrict__ e,
                                             const double* __restrict__ nrm64,
                                             const int* __restrict__ wlc,
                                             const int* __restrict__ wl,
                                             int* __restrict__ idx) {
    __shared__ float  xs[DDIM];
    __shared__ double w1[4]; __shared__ int wi[4];
    const int tid = threadIdx.x;
    const int lane = tid & 63;
    const int wv = tid >> 6;
    const int n = *wlc;

    for (int i = blockIdx.x; i < n; i += gridDim.x) {
        const int row = wl[i];
        if (tid < DDIM) xs[tid] = x[(size_t)row * DDIM + tid];
        __syncthreads();

        double dot[4] = {0.0, 0.0, 0.0, 0.0};
        for (int d0 = 0; d0 < DDIM; d0 += 8) {
            float ef[8][4];
            #pragma unroll
            for (int dd = 0; dd < 8; ++dd)
                #pragma unroll
                for (int kk = 0; kk < 4; ++kk)
                    ef[dd][kk] = e[(d0 + dd) * KCODES + tid + kk * 256];
            #pragma unroll
            for (int dd = 0; dd < 8; ++dd) {
                double xv = (double)xs[d0 + dd];
                #pragma unroll
                for (int kk = 0; kk < 4; ++kk)
                    dot[kk] = fma(xv, (double)ef[dd][kk], dot[kk]);
            }
        }

        double bb1 = 1e300; int bbi = 0;
        #pragma unroll
        for (int kk = 0; kk < 4; ++kk) {
            int k = tid + kk * 256;                  // ascending per thread
            double sc = nrm64[k] - 2.0 * dot[kk];
            if (sc < bb1) { bb1 = sc; bbi = k; }
        }
        #pragma unroll
        for (int m = 1; m < 64; m <<= 1) {
            double o1 = __shfl_xor(bb1, m);
            int    oi = __shfl_xor(bbi, m);
            bool take = (o1 < bb1) || (o1 == bb1 && oi < bbi);
            bb1 = take ? o1 : bb1;
            bbi = take ? oi : bbi;
        }
        if (lane == 0) { w1[wv] = bb1; wi[wv] = bbi; }
        __syncthreads();
        if (tid == 0) {
            double f1 = w1[0]; int fi = wi[0];
            #pragma unroll
            for (int j = 1; j < 4; ++j) {
                bool take = (w1[j] < f1) || (w1[j] == f1 && wi[j] < fi);
                f1 = take ? w1[j] : f1;
                fi = take ? wi[j] : fi;
            }
            idx[row] = fi;
        }
        __syncthreads();     // xs reused next iteration
    }
}

// ---------- gather + f32 STE ----------
__global__ void k_gather(const float* __restrict__ x, const float* __restrict__ et,
                         const int* __restrict__ idxp, float* __restrict__ out) {
    int gid = blockIdx.x * blockDim.x + threadIdx.x;   // NROWS*32
    int row = gid >> 5, d4 = gid & 31;
    float4 q = reinterpret_cast<const float4*>(et)[(size_t)idxp[row] * 32 + d4];
    float4 xv = reinterpret_cast<const float4*>(x)[gid];
    float4 o;
    o.x = xv.x + (q.x - xv.x);
    o.y = xv.y + (q.y - xv.y);
    o.z = xv.z + (q.z - xv.z);
    o.w = xv.w + (q.w - xv.w);
    reinterpret_cast<float4*>(out)[gid] = o;
}

extern "C" void kernel_launch(void* const* d_in, const int* in_sizes, int n_in,
                              void* d_out, int out_size, void* d_ws, size_t ws_size,
                              hipStream_t stream) {
    const float* x = (const float*)d_in[0];
    const float* e = (const float*)d_in[1];
    float* out = (float*)d_out;

    // ws layout (f32 slot units; all segments 16B-aligned). Total ~3.1 MB.
    double* nrm64 = (double*)d_ws;                       // 1024 d   (2048 slots)
    float*  et    = (float*)d_ws + 2048;                 // 131072
    float*  nrm   = et + 131072;                         // 1024
    int*    idx   = (int*)(nrm + 1024);                  // 65536
    int*    wlc   = idx + NROWS;                         // 4
    int*    wl    = wlc + 4;                             // 65536
    uint4*  epq   = (uint4*)(wl + NROWS);                // 32768 uint4 = 512 KB
    float*  pb1   = (float*)(epq + 32768);               // 2*65536
    float*  pb2   = pb1 + 2 * NROWS;                     // 2*65536
    int*    pbi   = (int*)(pb2 + 2 * NROWS);             // 2*65536

    hipMemsetAsync(wlc, 0, sizeof(int), stream);

    k_prep<<<512, 256, 0, stream>>>(e, et, nrm, nrm64, epq);
    k_argmin32<<<1024, 256, 0, stream>>>(x, epq, nrm, pb1, pb2, pbi);
    k_merge<<<NROWS / 256, 256, 0, stream>>>(pb1, pb2, pbi, idx, wlc, wl);
    k_fix<<<64, 256, 0, stream>>>(x, e, nrm64, wlc, wl, idx);
    k_gather<<<(NROWS * 32) / 256, 256, 0, stream>>>(x, et, idx, out);
}

// Round 6
// 122.474 us; speedup vs baseline: 1.0077x; 1.0077x over previous
//
#include <hip/hip_runtime.h>

// VectorQuantizer: x (64,32,32,128) f32, embeddings (128,1024) f32.
// out = x + (q - x), q = e.T[argmin_k ||x_row - e_k||^2]
//
// Cascade:
//   phase 1: split-bf16 MFMA (32x32x16): dot = xh.eh + xh.el + xl.eh (3 MFMAs,
//            f32 acc). score = nrm32[k] - 2*dot. sigma ~ 1e-4. Each wave owns one
//            32-row tile and scans all 1024 codes. gap < MARGIN1 -> worklist.
//   phase 2: f64 exact re-argmin of worklist rows (~40) (one row per block).
// Occupancy design: 128-thread blocks (2 waves), grid 1024, 20 KB LDS,
// VGPR <= 128  =>  16 waves/CU (4/SIMD) to hide MFMA dep-chains + DMA latency.
// A/B packed with the SAME k-bijection (dot invariant to consistent k-perm).
// C/D layout: col=lane&31, row=(reg&3)+8*(reg>>2)+4*(lane>>5)  [HW-verified].

#define NROWS 65536
#define DDIM 128
#define KCODES 1024
#define MARGIN1 0.004f

typedef __attribute__((ext_vector_type(8))) short short8;
typedef __attribute__((ext_vector_type(16))) float f32x16;

__device__ inline ushort f2bf(float f) {            // RNE f32 -> bf16 bits
    union { float f; unsigned u; } v; v.f = f;
    unsigned r = v.u + 0x7fffu + ((v.u >> 16) & 1u);
    return (ushort)(r >> 16);
}
__device__ inline float bf2f(ushort b) {
    union { unsigned u; float f; } v; v.u = ((unsigned)b) << 16;
    return v.f;
}

__device__ inline void gload_lds16(const uint4* g, uint4* lds) {
    __builtin_amdgcn_global_load_lds((const __attribute__((address_space(1))) void*)g,
                                     (__attribute__((address_space(3))) void*)lds,
                                     16, 0, 0);
}

// ---------- fused prep: transpose + norms + bf16 hi/lo pack ----------
__global__ void k_prep(const float* __restrict__ e, float* __restrict__ et,
                       float* __restrict__ nrm, double* __restrict__ nrm64,
                       uint4* __restrict__ epq) {
    const int gid = blockIdx.x * blockDim.x + threadIdx.x;

    // transpose (all threads): et[k][d] = e[d][k]
    {
        int d = gid >> 10, k = gid & 1023;
        et[k * DDIM + d] = e[gid];
    }

    // pack (first 32768 threads): epq slot = nt*1024 + h*512 + c*64 + lane
    if (gid < 32768) {
        int lane = gid & 63, c = (gid >> 6) & 7, h = (gid >> 9) & 1, nt = gid >> 10;
        int col = nt * 32 + (lane & 31);
        int kbase = c * 16 + ((lane >> 5) << 3);
        union { ushort u[8]; uint4 q; } pk;
        #pragma unroll
        for (int j = 0; j < 8; ++j) {
            float v = e[(kbase + j) * KCODES + col];
            ushort hb = f2bf(v);
            pk.u[j] = (h == 0) ? hb : f2bf(v - bf2f(hb));
        }
        epq[(size_t)nt * 1024 + h * 512 + c * 64 + lane] = pk.q;
    }

    // norms (threads 32768..40959): 8 lanes per code, 16 d each, shfl reduce
    if (gid >= 32768 && gid < 32768 + 8192) {
        int t2 = gid - 32768;
        int k = t2 >> 3, part = t2 & 7;
        double s = 0.0;
        #pragma unroll
        for (int j = 0; j < 16; ++j) {
            double v = (double)e[(part * 16 + j) * KCODES + k];
            s = fma(v, v, s);
        }
        #pragma unroll
        for (int m = 1; m < 8; m <<= 1) s += __shfl_xor(s, m);
        if (part == 0) { nrm64[k] = s; nrm[k] = (float)s; }
    }
}

// ---------- phase 1: split-bf16 MFMA argmin ----------
// grid 1024 x 128. Block = 2 waves = 2 rowtiles (64 rows). Each wave scans all
// 32 e-tiles. Single-buffer 16 KB LDS tile, DMA'd via global_load_lds;
// 8 blocks/CU resident hide the per-tile DMA drain.
__global__ __launch_bounds__(128, 4) void k_argmin32(const float* __restrict__ x,
                                                     const uint4* __restrict__ epq,
                                                     const float* __restrict__ nrm,
                                                     int* __restrict__ idx,
                                                     int* __restrict__ wlc,
                                                     int* __restrict__ wl) {
    __shared__ uint4 sbuf[1024];      // 16 KB: one e-tile (512 hi + 512 lo)
    __shared__ float snrm[KCODES];    // 4 KB

    const int tid = threadIdx.x;
    const int lane = tid & 63;
    const int w = tid >> 6;                    // rowtile in block
    const int rt = blockIdx.x * 2 + w;
    const int lrow = lane & 31;
    const int lgrp = lane >> 5;

    // stage norms into LDS (read per-tile on the post-MFMA critical path)
    #pragma unroll
    for (int j = 0; j < 8; ++j) snrm[j * 128 + tid] = nrm[j * 128 + tid];

    // A fragments (hi/lo): row = rt*32+lrow, k(c,j) = c*16 + lgrp*8 + j
    const float* xr = x + (size_t)(rt * 32 + lrow) * DDIM + (lgrp << 3);
    short8 ah[8], al[8];
    #pragma unroll
    for (int c = 0; c < 8; ++c) {
        float4 u = *reinterpret_cast<const float4*>(xr + c * 16);
        float4 v = *reinterpret_cast<const float4*>(xr + c * 16 + 4);
        float fv[8] = {u.x, u.y, u.z, u.w, v.x, v.y, v.z, v.w};
        short8 hi, lo;
        #pragma unroll
        for (int j = 0; j < 8; ++j) {
            ushort hb = f2bf(fv[j]);
            hi[j] = (short)hb;
            lo[j] = (short)f2bf(fv[j] - bf2f(hb));
        }
        ah[c] = hi; al[c] = lo;
    }

    float b1[16], b2[16]; int bi[16];
    #pragma unroll
    for (int r = 0; r < 16; ++r) { b1[r] = 3.4e38f; b2[r] = 3.4e38f; bi[r] = 0; }

    for (int t = 0; t < 32; ++t) {
        __syncthreads();              // sbuf free for overwrite (and snrm ready at t=0)
        #pragma unroll
        for (int i = 0; i < 8; ++i)
            gload_lds16(epq + (size_t)t * 1024 + i * 128 + tid,
                        &sbuf[i * 128 + (w << 6)]);     // wave-uniform LDS base
        asm volatile("s_waitcnt vmcnt(0)" ::: "memory");
        __syncthreads();              // tile visible to both waves

        const int code = t * 32 + lrow;
        const float nv = snrm[code];

        f32x16 acc;
        #pragma unroll
        for (int r = 0; r < 16; ++r) acc[r] = 0.f;

        #pragma unroll
        for (int c = 0; c < 8; ++c) {
            union { uint4 q; short8 s; } bh, bl;
            bh.q = sbuf[c * 64 + lane];
            bl.q = sbuf[512 + c * 64 + lane];
            acc = __builtin_amdgcn_mfma_f32_32x32x16_bf16(ah[c], bh.s, acc, 0, 0, 0);
            acc = __builtin_amdgcn_mfma_f32_32x32x16_bf16(ah[c], bl.s, acc, 0, 0, 0);
            acc = __builtin_amdgcn_mfma_f32_32x32x16_bf16(al[c], bh.s, acc, 0, 0, 0);
        }

        #pragma unroll
        for (int r = 0; r < 16; ++r) {
            float s = fmaf(-2.f, acc[r], nv);
            b2[r] = fminf(fmaxf(s, b1[r]), b2[r]);   // med3: new 2nd-best
            bool lt = s < b1[r];
            b1[r] = lt ? s : b1[r];
            bi[r] = lt ? code : bi[r];
        }
    }

    // butterfly over the 32 columns (each 32-lane half independently).
    // Equal-score cross-lane ties produce gap 0 -> flagged -> k_fix resolves.
    #pragma unroll
    for (int r = 0; r < 16; ++r) {
        #pragma unroll
        for (int m = 1; m < 32; m <<= 1) {
            float o1 = __shfl_xor(b1[r], m);
            float o2 = __shfl_xor(b2[r], m);
            int   oi = __shfl_xor(bi[r], m);
            bool take = (o1 < b1[r]) || (o1 == b1[r] && oi < bi[r]);
            float loser = take ? b1[r] : o1;
            b1[r] = take ? o1 : b1[r];
            bi[r] = take ? oi : bi[r];
            b2[r] = fminf(fminf(b2[r], o2), loser);
        }
    }

    if (lrow == 0) {
        #pragma unroll
        for (int r = 0; r < 16; ++r) {
            int rl = (r & 3) + 8 * (r >> 2) + 4 * lgrp;   // HW-verified C/D row map
            int row = rt * 32 + rl;
            idx[row] = bi[r];
            if (b2[r] - b1[r] < MARGIN1) {
                int slot = atomicAdd(wlc, 1);
                wl[slot] = row;
            }
        }
    }
}

// ---------- phase 2: exact f64 re-argmin, one row per block ----------
__global__ __launch_bounds__(256) void k_fix(const float* __restrict__ x,
                                             const float* __restrict__ e,
                                             const double* __restrict__ nrm64,
                                             const int* __restrict__ wlc,
                                             const int* __restrict__ wl,
                                             int* __restrict__ idx) {
    __shared__ float  xs[DDIM];
    __shared__ double w1[4]; __shared__ int wi[4];
    const int tid = threadIdx.x;
    const int lane = tid & 63;
    const int wv = tid >> 6;
    const int n = *wlc;

    for (int i = blockIdx.x; i < n; i += gridDim.x) {
        const int row = wl[i];
        if (tid < DDIM) xs[tid] = x[(size_t)row * DDIM + tid];
        __syncthreads();

        double dot[4] = {0.0, 0.0, 0.0, 0.0};
        for (int d0 = 0; d0 < DDIM; d0 += 8) {
            float ef[8][4];
            #pragma unroll
            for (int dd = 0; dd < 8; ++dd)
                #pragma unroll
                for (int kk = 0; kk < 4; ++kk)
                    ef[dd][kk] = e[(d0 + dd) * KCODES + tid + kk * 256];
            #pragma unroll
            for (int dd = 0; dd < 8; ++dd) {
                double xv = (double)xs[d0 + dd];
                #pragma unroll
                for (int kk = 0; kk < 4; ++kk)
                    dot[kk] = fma(xv, (double)ef[dd][kk], dot[kk]);
            }
        }

        double bb1 = 1e300; int bbi = 0;
        #pragma unroll
        for (int kk = 0; kk < 4; ++kk) {
            int k = tid + kk * 256;                  // ascending per thread
            double sc = nrm64[k] - 2.0 * dot[kk];
            if (sc < bb1) { bb1 = sc; bbi = k; }
        }
        #pragma unroll
        for (int m = 1; m < 64; m <<= 1) {
            double o1 = __shfl_xor(bb1, m);
            int    oi = __shfl_xor(bbi, m);
            bool take = (o1 < bb1) || (o1 == bb1 && oi < bbi);
            bb1 = take ? o1 : bb1;
            bbi = take ? oi : bbi;
        }
        if (lane == 0) { w1[wv] = bb1; wi[wv] = bbi; }
        __syncthreads();
        if (tid == 0) {
            double f1 = w1[0]; int fi = wi[0];
            #pragma unroll
            for (int j = 1; j < 4; ++j) {
                bool take = (w1[j] < f1) || (w1[j] == f1 && wi[j] < fi);
                f1 = take ? w1[j] : f1;
                fi = take ? wi[j] : fi;
            }
            idx[row] = fi;
        }
        __syncthreads();     // xs reused next iteration
    }
}

// ---------- gather + f32 STE ----------
__global__ void k_gather(const float* __restrict__ x, const float* __restrict__ et,
                         const int* __restrict__ idxp, float* __restrict__ out) {
    int gid = blockIdx.x * blockDim.x + threadIdx.x;   // NROWS*32
    int row = gid >> 5, d4 = gid & 31;
    float4 q = reinterpret_cast<const float4*>(et)[(size_t)idxp[row] * 32 + d4];
    float4 xv = reinterpret_cast<const float4*>(x)[gid];
    float4 o;
    o.x = xv.x + (q.x - xv.x);
    o.y = xv.y + (q.y - xv.y);
    o.z = xv.z + (q.z - xv.z);
    o.w = xv.w + (q.w - xv.w);
    reinterpret_cast<float4*>(out)[gid] = o;
}

extern "C" void kernel_launch(void* const* d_in, const int* in_sizes, int n_in,
                              void* d_out, int out_size, void* d_ws, size_t ws_size,
                              hipStream_t stream) {
    const float* x = (const float*)d_in[0];
    const float* e = (const float*)d_in[1];
    float* out = (float*)d_out;

    // ws layout (f32 slot units; all segments 16B-aligned)
    double* nrm64 = (double*)d_ws;                       // 1024 d   (2048 slots)
    float*  et    = (float*)d_ws + 2048;                 // 131072
    float*  nrm   = et + 131072;                         // 1024
    int*    idx   = (int*)(nrm + 1024);                  // 65536
    int*    wlc   = idx + NROWS;                         // 4
    int*    wl    = wlc + 4;                             // 65536
    uint4*  epq   = (uint4*)(wl + NROWS);                // 32768 uint4 = 512 KB

    hipMemsetAsync(wlc, 0, sizeof(int), stream);

    k_prep<<<512, 256, 0, stream>>>(e, et, nrm, nrm64, epq);
    k_argmin32<<<1024, 128, 0, stream>>>(x, epq, nrm, idx, wlc, wl);
    k_fix<<<64, 256, 0, stream>>>(x, e, nrm64, wlc, wl, idx);
    k_gather<<<(NROWS * 32) / 256, 256, 0, stream>>>(x, et, idx, out);
}

// Round 7
// 108.592 us; speedup vs baseline: 1.1365x; 1.1278x over previous
//
#include <hip/hip_runtime.h>

// VectorQuantizer: x (64,32,32,128) f32, embeddings (128,1024) f32.
// out = x + (q - x), q = e.T[argmin_k ||x_row - e_k||^2]
//
// phase 1: split-bf16 MFMA (32x32x16): dot = xh.eh + xh.el + xl.eh, f32 acc
//          in 2 independent chains. score = nrm32[k] - 2*dot (sigma ~1e-4).
//          Grid = 512 rowgroups x 2 code-halves; 4-wave blocks; e-tiles
//          double-buffered in LDS via global_load_lds.
// merge  : combine halves per row; gap < MARGIN1 -> worklist (~40 rows).
// phase 2: f64 exact re-argmin of worklist rows.
//
// Register discipline (r5/r6 post-mortem): gfx950 unified VGPR+AGPR file --
// tight launch_bounds mins cap the TOTAL file and AGPRs round up, so (..,4)
// left only 64 arch VGPRs -> spill catastrophe. Use (256,2): cap 256, no
// spill possible; actual ~150 => 3 waves/SIMD at runtime.
// A/B packed with the SAME k-bijection (dot invariant to consistent k-perm).
// C/D layout: col=lane&31, row=(reg&3)+8*(reg>>2)+4*(lane>>5)  [HW-verified].

#define NROWS 65536
#define DDIM 128
#define KCODES 1024
#define MARGIN1 0.004f

typedef __attribute__((ext_vector_type(8))) short short8;
typedef __attribute__((ext_vector_type(16))) float f32x16;

__device__ inline ushort f2bf(float f) {            // RNE f32 -> bf16 bits
    union { float f; unsigned u; } v; v.f = f;
    unsigned r = v.u + 0x7fffu + ((v.u >> 16) & 1u);
    return (ushort)(r >> 16);
}
__device__ inline float bf2f(ushort b) {
    union { unsigned u; float f; } v; v.u = ((unsigned)b) << 16;
    return v.f;
}

__device__ inline void gload_lds16(const uint4* g, uint4* lds) {
    __builtin_amdgcn_global_load_lds((const __attribute__((address_space(1))) void*)g,
                                     (__attribute__((address_space(3))) void*)lds,
                                     16, 0, 0);
}

// ---------- fused prep: transpose + norms + bf16 hi/lo pack ----------
__global__ void k_prep(const float* __restrict__ e, float* __restrict__ et,
                       float* __restrict__ nrm, double* __restrict__ nrm64,
                       uint4* __restrict__ epq) {
    const int gid = blockIdx.x * blockDim.x + threadIdx.x;

    // transpose (all threads): et[k][d] = e[d][k]
    {
        int d = gid >> 10, k = gid & 1023;
        et[k * DDIM + d] = e[gid];
    }

    // pack (first 32768 threads): epq slot = nt*1024 + h*512 + c*64 + lane
    if (gid < 32768) {
        int lane = gid & 63, c = (gid >> 6) & 7, h = (gid >> 9) & 1, nt = gid >> 10;
        int col = nt * 32 + (lane & 31);
        int kbase = c * 16 + ((lane >> 5) << 3);
        union { ushort u[8]; uint4 q; } pk;
        #pragma unroll
        for (int j = 0; j < 8; ++j) {
            float v = e[(kbase + j) * KCODES + col];
            ushort hb = f2bf(v);
            pk.u[j] = (h == 0) ? hb : f2bf(v - bf2f(hb));
        }
        epq[(size_t)nt * 1024 + h * 512 + c * 64 + lane] = pk.q;
    }

    // norms (threads 32768..40959): 8 lanes per code, 16 d each, shfl reduce
    if (gid >= 32768 && gid < 32768 + 8192) {
        int t2 = gid - 32768;
        int k = t2 >> 3, part = t2 & 7;
        double s = 0.0;
        #pragma unroll
        for (int j = 0; j < 16; ++j) {
            double v = (double)e[(part * 16 + j) * KCODES + k];
            s = fma(v, v, s);
        }
        #pragma unroll
        for (int m = 1; m < 8; m <<= 1) s += __shfl_xor(s, m);
        if (part == 0) { nrm64[k] = s; nrm[k] = (float)s; }
    }
}

// ---------- phase 1: split-bf16 MFMA argmin, k-split x2, dbuf DMA ----------
// grid 1024 = 512 rowgroups x 2 code-halves. Block = 4 waves = 4 rowtiles
// (128 rows); each block scans its 16 e-tiles (512 codes).
__global__ __launch_bounds__(256, 2) void k_argmin32(const float* __restrict__ x,
                                                     const uint4* __restrict__ epq,
                                                     const float* __restrict__ nrm,
                                                     float* __restrict__ pb1,
                                                     float* __restrict__ pb2,
                                                     int* __restrict__ pbi) {
    __shared__ uint4 sbuf[2][1024];   // 32 KB: 2 x (512 hi + 512 lo)
    __shared__ float snrm[512];       // 2 KB: this half's norms

    const int tid = threadIdx.x;
    const int lane = tid & 63;
    const int w = tid >> 6;                    // rowtile in block
    const int kh = blockIdx.x & 1;             // code half
    const int rg = blockIdx.x >> 1;
    const int rt = rg * 4 + w;
    const int lrow = lane & 31;
    const int lgrp = lane >> 5;
    const int tbase = kh * 16;

    // prologue: DMA tile 0 into sbuf[0] (4 x 16B per thread)
    #pragma unroll
    for (int i = 0; i < 4; ++i)
        gload_lds16(epq + (size_t)tbase * 1024 + i * 256 + tid,
                    &sbuf[0][i * 256 + (w << 6)]);

    // stage this half's norms
    snrm[tid] = nrm[kh * 512 + tid];
    snrm[256 + tid] = nrm[kh * 512 + 256 + tid];

    // A fragments (hi/lo): row = rt*32+lrow, k(c,j) = c*16 + lgrp*8 + j
    const float* xr = x + (size_t)(rt * 32 + lrow) * DDIM + (lgrp << 3);
    short8 ah[8], al[8];
    #pragma unroll
    for (int c = 0; c < 8; ++c) {
        float4 u = *reinterpret_cast<const float4*>(xr + c * 16);
        float4 v = *reinterpret_cast<const float4*>(xr + c * 16 + 4);
        float fv[8] = {u.x, u.y, u.z, u.w, v.x, v.y, v.z, v.w};
        short8 hi, lo;
        #pragma unroll
        for (int j = 0; j < 8; ++j) {
            ushort hb = f2bf(fv[j]);
            hi[j] = (short)hb;
            lo[j] = (short)f2bf(fv[j] - bf2f(hb));
        }
        ah[c] = hi; al[c] = lo;
    }

    float b1[16], b2[16]; int bi[16];
    #pragma unroll
    for (int r = 0; r < 16; ++r) { b1[r] = 3.4e38f; b2[r] = 3.4e38f; bi[r] = 0; }

    __syncthreads();                  // tile 0 + snrm ready

    int cur = 0;
    for (int t = 0; t < 16; ++t) {
        if (t + 1 < 16) {             // prefetch next tile into other buffer
            #pragma unroll
            for (int i = 0; i < 4; ++i)
                gload_lds16(epq + (size_t)(tbase + t + 1) * 1024 + i * 256 + tid,
                            &sbuf[cur ^ 1][i * 256 + (w << 6)]);
        }
        const int lcode = t * 32 + lrow;          // code within half
        const float nv = snrm[lcode];
        const int code = kh * 512 + lcode;

        f32x16 accA, accB;            // 2 independent dep chains
        #pragma unroll
        for (int r = 0; r < 16; ++r) { accA[r] = 0.f; accB[r] = 0.f; }

        #pragma unroll
        for (int c = 0; c < 8; ++c) {
            union { uint4 q; short8 s; } bh, bl;
            bh.q = sbuf[cur][c * 64 + lane];
            bl.q = sbuf[cur][512 + c * 64 + lane];
            accA = __builtin_amdgcn_mfma_f32_32x32x16_bf16(ah[c], bh.s, accA, 0, 0, 0);
            accA = __builtin_amdgcn_mfma_f32_32x32x16_bf16(ah[c], bl.s, accA, 0, 0, 0);
            accB = __builtin_amdgcn_mfma_f32_32x32x16_bf16(al[c], bh.s, accB, 0, 0, 0);
        }

        #pragma unroll
        for (int r = 0; r < 16; ++r) {
            float s = fmaf(-2.f, accA[r] + accB[r], nv);
            b2[r] = fminf(fmaxf(s, b1[r]), b2[r]);   // new 2nd-best
            bool lt = s < b1[r];
            b1[r] = lt ? s : b1[r];
            bi[r] = lt ? code : bi[r];
        }
        __syncthreads();              // drains DMA + guards buffer swap
        cur ^= 1;
    }

    // butterfly over the 32 columns (each 32-lane half independently).
    // Equal-score cross-lane ties give gap 0 -> flagged -> k_fix resolves.
    #pragma unroll
    for (int r = 0; r < 16; ++r) {
        #pragma unroll
        for (int m = 1; m < 32; m <<= 1) {
            float o1 = __shfl_xor(b1[r], m);
            float o2 = __shfl_xor(b2[r], m);
            int   oi = __shfl_xor(bi[r], m);
            bool take = (o1 < b1[r]) || (o1 == b1[r] && oi < bi[r]);
            float loser = take ? b1[r] : o1;
            b1[r] = take ? o1 : b1[r];
            bi[r] = take ? oi : bi[r];
            b2[r] = fminf(fminf(b2[r], o2), loser);
        }
    }

    if (lrow == 0) {
        #pragma unroll
        for (int r = 0; r < 16; ++r) {
            int rl = (r & 3) + 8 * (r >> 2) + 4 * lgrp;   // HW-verified C/D row map
            size_t o = (size_t)kh * NROWS + rt * 32 + rl;
            pb1[o] = b1[r]; pb2[o] = b2[r]; pbi[o] = bi[r];
        }
    }
}

// ---------- merge the 2 code-halves per row ----------
__global__ void k_merge(const float* __restrict__ pb1, const float* __restrict__ pb2,
                        const int* __restrict__ pbi, int* __restrict__ idx,
                        int* __restrict__ wlc, int* __restrict__ wl) {
    int r = blockIdx.x * blockDim.x + threadIdx.x;     // 0..NROWS-1
    float a1 = pb1[r], a2 = pb2[r];
    int   ai = pbi[r];
    float c1 = pb1[NROWS + r], c2 = pb2[NROWS + r];
    int   ci = pbi[NROWS + r];
    bool take = c1 < a1;                // tie -> half 0 (all its codes are lower)
    float f1 = take ? c1 : a1;
    int   fi = take ? ci : ai;
    float loser = take ? a1 : c1;
    float f2 = fminf(fminf(a2, c2), loser);
    idx[r] = fi;
    if (f2 - f1 < MARGIN1) {
        int slot = atomicAdd(wlc, 1);
        wl[slot] = r;
    }
}

// ---------- phase 2: exact f64 re-argmin, one row per block ----------
__global__ __launch_bounds__(256) void k_fix(const float* __restrict__ x,
                                             const float* __restrict__ e,
                                             const double* __restrict__ nrm64,
                                             const int* __restrict__ wlc,
                                             const int* __restrict__ wl,
                                             int* __restrict__ idx) {
    __shared__ float  xs[DDIM];
    __shared__ double w1[4]; __shared__ int wi[4];
    const int tid = threadIdx.x;
    const int lane = tid & 63;
    const int wv = tid >> 6;
    const int n = *wlc;

    for (int i = blockIdx.x; i < n; i += gridDim.x) {
        const int row = wl[i];
        if (tid < DDIM) xs[tid] = x[(size_t)row * DDIM + tid];
        __syncthreads();

        double dot[4] = {0.0, 0.0, 0.0, 0.0};
        for (int d0 = 0; d0 < DDIM; d0 += 8) {
            float ef[8][4];
            #pragma unroll
            for (int dd = 0; dd < 8; ++dd)
                #pragma unroll
                for (int kk = 0; kk < 4; ++kk)
                    ef[dd][kk] = e[(d0 + dd) * KCODES + tid + kk * 256];
            #pragma unroll
            for (int dd = 0; dd < 8; ++dd) {
                double xv = (double)xs[d0 + dd];
                #pragma unroll
                for (int kk = 0; kk < 4; ++kk)
                    dot[kk] = fma(xv, (double)ef[dd][kk], dot[kk]);
            }
        }

        double bb1 = 1e300; int bbi = 0;
        #pragma unroll
        for (int kk = 0; kk < 4; ++kk) {
            int k = tid + kk * 256;                  // ascending per thread
            double sc = nrm64[k] - 2.0 * dot[kk];
            if (sc < bb1) { bb1 = sc; bbi = k; }
        }
        #pragma unroll
        for (int m = 1; m < 64; m <<= 1) {
            double o1 = __shfl_xor(bb1, m);
            int    oi = __shfl_xor(bbi, m);
            bool take = (o1 < bb1) || (o1 == bb1 && oi < bbi);
            bb1 = take ? o1 : bb1;
            bbi = take ? oi : bbi;
        }
        if (lane == 0) { w1[wv] = bb1; wi[wv] = bbi; }
        __syncthreads();
        if (tid == 0) {
            double f1 = w1[0]; int fi = wi[0];
            #pragma unroll
            for (int j = 1; j < 4; ++j) {
                bool take = (w1[j] < f1) || (w1[j] == f1 && wi[j] < fi);
                f1 = take ? w1[j] : f1;
                fi = take ? wi[j] : fi;
            }
            idx[row] = fi;
        }
        __syncthreads();     // xs reused next iteration
    }
}

// ---------- gather + f32 STE ----------
__global__ void k_gather(const float* __restrict__ x, const float* __restrict__ et,
                         const int* __restrict__ idxp, float* __restrict__ out) {
    int gid = blockIdx.x * blockDim.x + threadIdx.x;   // NROWS*32
    int row = gid >> 5, d4 = gid & 31;
    float4 q = reinterpret_cast<const float4*>(et)[(size_t)idxp[row] * 32 + d4];
    float4 xv = reinterpret_cast<const float4*>(x)[gid];
    float4 o;
    o.x = xv.x + (q.x - xv.x);
    o.y = xv.y + (q.y - xv.y);
    o.z = xv.z + (q.z - xv.z);
    o.w = xv.w + (q.w - xv.w);
    reinterpret_cast<float4*>(out)[gid] = o;
}

extern "C" void kernel_launch(void* const* d_in, const int* in_sizes, int n_in,
                              void* d_out, int out_size, void* d_ws, size_t ws_size,
                              hipStream_t stream) {
    const float* x = (const float*)d_in[0];
    const float* e = (const float*)d_in[1];
    float* out = (float*)d_out;

    // ws layout (f32 slot units; all segments 16B-aligned)
    double* nrm64 = (double*)d_ws;                       // 1024 d   (2048 slots)
    float*  et    = (float*)d_ws + 2048;                 // 131072
    float*  nrm   = et + 131072;                         // 1024
    int*    idx   = (int*)(nrm + 1024);                  // 65536
    int*    wlc   = idx + NROWS;                         // 4
    int*    wl    = wlc + 4;                             // 65536
    uint4*  epq   = (uint4*)(wl + NROWS);                // 32768 uint4 = 512 KB
    float*  pb1   = (float*)(epq + 32768);               // 2*65536
    float*  pb2   = pb1 + 2 * NROWS;                     // 2*65536
    int*    pbi   = (int*)(pb2 + 2 * NROWS);             // 2*65536

    hipMemsetAsync(wlc, 0, sizeof(int), stream);

    k_prep<<<512, 256, 0, stream>>>(e, et, nrm, nrm64, epq);
    k_argmin32<<<1024, 256, 0, stream>>>(x, epq, nrm, pb1, pb2, pbi);
    k_merge<<<NROWS / 256, 256, 0, stream>>>(pb1, pb2, pbi, idx, wlc, wl);
    k_fix<<<64, 256, 0, stream>>>(x, e, nrm64, wlc, wl, idx);
    k_gather<<<(NROWS * 32) / 256, 256, 0, stream>>>(x, et, idx, out);
}